// Round 10
// baseline (391.582 us; speedup 1.0000x reference)
//
#include <hip/hip_runtime.h>
#include <hip/hip_fp16.h>
#include <math.h>

typedef _Float16 h16_t;
typedef __attribute__((ext_vector_type(4))) _Float16 h16x4;
typedef __attribute__((ext_vector_type(8))) _Float16 h16x8;
typedef __attribute__((ext_vector_type(4))) float f32x4;

static_assert(sizeof(h16_t) == 2, "f16 size");

__device__ __forceinline__ f32x4 mfma16(h16x8 a, h16x8 b, f32x4 c) {
  return __builtin_amdgcn_mfma_f32_16x16x32_f16(a, b, c, 0, 0, 0);
}

__device__ __forceinline__ h16x8 cvt8(float4 a, float4 b) {
  h16x8 o;
  o[0] = (h16_t)a.x; o[1] = (h16_t)a.y; o[2] = (h16_t)a.z; o[3] = (h16_t)a.w;
  o[4] = (h16_t)b.x; o[5] = (h16_t)b.y; o[6] = (h16_t)b.z; o[7] = (h16_t)b.w;
  return o;
}

// bank-conflict-free LDS chunk key (verified per 8-lane phase for K-rows,
// V-rows and linear staging writes)
#define SWKEY(r) ((((r) & 3) << 1) | ((((r) >> 2) ^ ((r) >> 3)) & 1))

// ---------------------------------------------------------------------------
// GEMM: W staged from F32 through double-buffered 128-col segments (2x16KB).
// A supplied by a per-lane lambda returning the h16x8 fragment for k-base kb.
// ---------------------------------------------------------------------------
template <int K, typename AL>
__device__ __forceinline__ void gemm_runf(AL loadA, const float* __restrict__ W,
                                          int o0, h16_t* wl, f32x4* acc) {
  constexpr int NS = K / 128;
  const int lane = threadIdx.x & 63;
  const int l15 = lane & 15;
  const int quad = lane >> 4;
  int sr[4], sc[4], sd[4];
#pragma unroll
  for (int i = 0; i < 4; ++i) {
    const int id = threadIdx.x + i * 256;
    const int row = id >> 4, c = id & 15;
    sr[i] = row;
    sc[i] = c * 8;
    sd[i] = (row * 16 + (c ^ (row & 7))) * 8;
  }
  float4 wa[4], wb[4];
#pragma unroll
  for (int i = 0; i < 4; ++i) {
    const float* s = W + (size_t)(o0 + sr[i]) * K + sc[i];
    wa[i] = *(const float4*)s;
    wb[i] = *(const float4*)(s + 4);
  }
#pragma unroll
  for (int i = 0; i < 4; ++i) *(h16x8*)(wl + sd[i]) = cvt8(wa[i], wb[i]);
  __syncthreads();
#pragma unroll
  for (int sg = 0; sg < NS; ++sg) {
    if (sg + 1 < NS) {
#pragma unroll
      for (int i = 0; i < 4; ++i) {
        const float* s = W + (size_t)(o0 + sr[i]) * K + (sg + 1) * 128 + sc[i];
        wa[i] = *(const float4*)s;
        wb[i] = *(const float4*)(s + 4);
      }
    }
    const h16_t* wp = wl + (sg & 1) * 8192;
#pragma unroll
    for (int ks = 0; ks < 4; ++ks) {
      h16x8 af = loadA(sg * 128 + ks * 32 + quad * 8);
#pragma unroll
      for (int j = 0; j < 4; ++j) {
        h16x8 wf = *(const h16x8*)(
            wp + (size_t)((j * 16 + l15) * 16 + ((ks * 4 + quad) ^ (l15 & 7))) * 8);
        acc[j] = mfma16(af, wf, acc[j]);
      }
    }
    if (sg + 1 < NS) {
      h16_t* wn = wl + ((sg + 1) & 1) * 8192;
#pragma unroll
      for (int i = 0; i < 4; ++i) *(h16x8*)(wn + sd[i]) = cvt8(wa[i], wb[i]);
    }
    __syncthreads();
  }
}

#define EPILOGUE_SETUP()                            \
  const int wv = threadIdx.x >> 6;                  \
  const int lane = threadIdx.x & 63;                \
  const int l15 = lane & 15;                        \
  const int quad = lane >> 4;                       \
  const int m0 = blockIdx.x * 64 + wv * 16;         \
  const int o0 = blockIdx.y * 64;                   \
  f32x4 acc[4];                                     \
  for (int j = 0; j < 4; ++j) acc[j] = f32x4{0.f, 0.f, 0.f, 0.f};

// qkv = x(f32) @ w_qkv(f32).T ; split q,k (b,h,n,d) and v transposed (b,h,d,n)
__global__ __launch_bounds__(256) void k_gemm_qkv(
    const float* __restrict__ X, const float* __restrict__ W,
    h16_t* __restrict__ qb, h16_t* __restrict__ kb, h16_t* __restrict__ vT) {
  __shared__ h16_t wl[2 * 8192];
  EPILOGUE_SETUP();
  const float* ap = X + (size_t)(m0 + l15) * 512;
  gemm_runf<512>(
      [&](int kbase) -> h16x8 {
        float4 u = *(const float4*)(ap + kbase);
        float4 v = *(const float4*)(ap + kbase + 4);
        return cvt8(u, v);
      },
      W, o0, wl, acc);
#pragma unroll
  for (int j = 0; j < 4; ++j)
#pragma unroll
    for (int r = 0; r < 4; ++r) {
      const int o = o0 + j * 16 + l15;
      const int m = m0 + quad * 4 + r;
      const int b = m >> 10, n = m & 1023;
      const int oo = o & 511, h = oo >> 6, d = oo & 63;
      const size_t bh = (size_t)(b * 8 + h);
      const h16_t v = (h16_t)acc[j][r];
      if (o < 512)
        qb[(bh * 1024 + n) * 64 + d] = v;
      else if (o < 1024)
        kb[(bh * 1024 + n) * 64 + d] = v;
      else
        vT[(bh * 64 + d) * 1024 + n] = v;
    }
}

// L0: A = normalize(ck/cv) fused in-register (f32 src x inv), LeakyReLU, z-merged
__global__ __launch_bounds__(256) void k_gemm_l0(
    const float* __restrict__ ck, const float* __restrict__ cv,
    const float* __restrict__ invck,
    const float* __restrict__ wck, const float* __restrict__ wcv,
    const float* __restrict__ bck, const float* __restrict__ bcv,
    h16_t* __restrict__ yck, h16_t* __restrict__ ycv) {
  __shared__ h16_t wl[2 * 8192];
  EPILOGUE_SETUP();
  const int z = blockIdx.z;
  const float* W = z ? wcv : wck;
  const float* bias = z ? bcv : bck;
  h16_t* Y = z ? ycv : yck;
  const int m = m0 + l15, b = m >> 10, n = m & 1023;
  const float* iv = invck + z * 3072 + b * 384;
  const float* sb = (z ? cv : ck) + (size_t)(b * 6) * 65536 + (size_t)n * 64;
  gemm_runf<384>(
      [&](int kbase) -> h16x8 {
        const float* s = sb + (size_t)(kbase >> 6) * 65536 + (kbase & 63);
        float4 u = *(const float4*)s, v = *(const float4*)(s + 4);
        float4 i0 = *(const float4*)(iv + kbase), i1 = *(const float4*)(iv + kbase + 4);
        u.x *= i0.x; u.y *= i0.y; u.z *= i0.z; u.w *= i0.w;
        v.x *= i1.x; v.y *= i1.y; v.z *= i1.z; v.w *= i1.w;
        return cvt8(u, v);
      },
      W, o0, wl, acc);
#pragma unroll
  for (int j = 0; j < 4; ++j)
#pragma unroll
    for (int r = 0; r < 4; ++r) {
      const int o = o0 + j * 16 + l15;
      const int mm = m0 + quad * 4 + r;
      float v = acc[j][r] + bias[o];
      v = v > 0.f ? v : 0.2f * v;
      Y[(size_t)mm * 512 + o] = (h16_t)v;
    }
}

// L1: f16 A, LeakyReLU, layout 0, z-merged
__global__ __launch_bounds__(256) void k_gemm_l1(
    const h16_t* __restrict__ a0, const h16_t* __restrict__ a1,
    const float* __restrict__ w0, const float* __restrict__ w1,
    const float* __restrict__ b0, const float* __restrict__ b1,
    h16_t* __restrict__ y0, h16_t* __restrict__ y1) {
  __shared__ h16_t wl[2 * 8192];
  EPILOGUE_SETUP();
  const int z = blockIdx.z;
  const h16_t* ap = (z ? a1 : a0) + (size_t)(m0 + l15) * 512;
  const float* W = z ? w1 : w0;
  const float* bias = z ? b1 : b0;
  h16_t* Y = z ? y1 : y0;
  gemm_runf<512>([&](int kbase) -> h16x8 { return *(const h16x8*)(ap + kbase); },
                 W, o0, wl, acc);
#pragma unroll
  for (int j = 0; j < 4; ++j)
#pragma unroll
    for (int r = 0; r < 4; ++r) {
      const int o = o0 + j * 16 + l15;
      const int mm = m0 + quad * 4 + r;
      float v = acc[j][r] + bias[o];
      v = v > 0.f ? v : 0.2f * v;
      Y[(size_t)mm * 512 + o] = (h16_t)v;
    }
}

// L2: f16 A, LeakyReLU; z=0 -> ckh (b,h,n,d), z=1 -> cvT (b,h,d,n)
__global__ __launch_bounds__(256) void k_gemm_l2(
    const h16_t* __restrict__ a0, const h16_t* __restrict__ a1,
    const float* __restrict__ w0, const float* __restrict__ w1,
    const float* __restrict__ b0, const float* __restrict__ b1,
    h16_t* __restrict__ y0, h16_t* __restrict__ y1) {
  __shared__ h16_t wl[2 * 8192];
  EPILOGUE_SETUP();
  const int z = blockIdx.z;
  const h16_t* ap = (z ? a1 : a0) + (size_t)(m0 + l15) * 512;
  const float* W = z ? w1 : w0;
  const float* bias = z ? b1 : b0;
#pragma unroll
  for (int j = 0; j < 4; ++j) acc[j] = f32x4{0.f, 0.f, 0.f, 0.f};
  gemm_runf<512>([&](int kbase) -> h16x8 { return *(const h16x8*)(ap + kbase); },
                 W, o0, wl, acc);
#pragma unroll
  for (int j = 0; j < 4; ++j)
#pragma unroll
    for (int r = 0; r < 4; ++r) {
      const int o = o0 + j * 16 + l15;
      const int mm = m0 + quad * 4 + r;
      float v = acc[j][r] + bias[o];
      v = v > 0.f ? v : 0.2f * v;
      const int b = mm >> 10, n = mm & 1023;
      const int h = o >> 6, d = o & 63;
      if (!z)
        y0[((size_t)(b * 8 + h) * 1024 + n) * 64 + d] = (h16_t)v;
      else
        y1[((size_t)(b * 8 + h) * 64 + d) * 1024 + n] = (h16_t)v;
    }
}

// nl: A = S3 x inv_rm (fused), gelu, combine with attn, f16 out
__global__ __launch_bounds__(256) void k_gemm_nl(
    const h16_t* __restrict__ S, const float* __restrict__ invrm,
    const float* __restrict__ W, const float* __restrict__ bias,
    const h16_t* __restrict__ attn, const float* __restrict__ subr,
    h16_t* __restrict__ Y) {
  __shared__ h16_t wl[2 * 8192];
  EPILOGUE_SETUP();
  const int m = m0 + l15, b = m >> 10;
  const h16_t* ap = S + (size_t)m * 512;
  const float* iv = invrm + b * 512;
  gemm_runf<512>(
      [&](int kbase) -> h16x8 {
        h16x8 a = *(const h16x8*)(ap + kbase);
        float4 i0 = *(const float4*)(iv + kbase), i1 = *(const float4*)(iv + kbase + 4);
        h16x8 o;
        o[0] = (h16_t)((float)a[0] * i0.x); o[1] = (h16_t)((float)a[1] * i0.y);
        o[2] = (h16_t)((float)a[2] * i0.z); o[3] = (h16_t)((float)a[3] * i0.w);
        o[4] = (h16_t)((float)a[4] * i1.x); o[5] = (h16_t)((float)a[5] * i1.y);
        o[6] = (h16_t)((float)a[6] * i1.z); o[7] = (h16_t)((float)a[7] * i1.w);
        return o;
      },
      W, o0, wl, acc);
#pragma unroll
  for (int j = 0; j < 4; ++j)
#pragma unroll
    for (int r = 0; r < 4; ++r) {
      const int o = o0 + j * 16 + l15;
      const int mm = m0 + quad * 4 + r;
      const float v = acc[j][r] + bias[o];
      const float g = 0.5f * v * (1.f + erff(v * 0.70710678118654752f));
      const float res = (float)attn[(size_t)mm * 512 + o] - g * subr[o];
      Y[(size_t)mm * 512 + o] = (h16_t)res;
    }
}

// out: f16 A, f32 W, f32 output + bias
__global__ __launch_bounds__(256) void k_gemm_out(
    const h16_t* __restrict__ A, const float* __restrict__ W,
    const float* __restrict__ bias, float* __restrict__ Y) {
  __shared__ h16_t wl[2 * 8192];
  EPILOGUE_SETUP();
  const h16_t* ap = A + (size_t)(m0 + l15) * 512;
  gemm_runf<512>([&](int kbase) -> h16x8 { return *(const h16x8*)(ap + kbase); },
                 W, o0, wl, acc);
#pragma unroll
  for (int j = 0; j < 4; ++j)
#pragma unroll
    for (int r = 0; r < 4; ++r) {
      const int o = o0 + j * 16 + l15;
      const int mm = m0 + quad * 4 + r;
      Y[(size_t)mm * 512 + o] = acc[j][r] + bias[o];
    }
}

// ---------------------------------------------------------------------------
// Attention (round-9 verified structure; new conflict-free swizzle key; z=1
// additionally emits per-wave partial sums of O^2 over q-rows for the fused
// rm-norm -> part2[((b*8+qx)*4+wv)*512 + f], deterministic stores).
// ---------------------------------------------------------------------------
__global__ __launch_bounds__(256) void k_attn4(
    const h16_t* __restrict__ q,
    const h16_t* __restrict__ k0, const h16_t* __restrict__ v0, h16_t* __restrict__ out0,
    const h16_t* __restrict__ k1, const h16_t* __restrict__ v1, h16_t* __restrict__ out1,
    float* __restrict__ part2) {
  const int wv = threadIdx.x >> 6;
  const int lane = threadIdx.x & 63;
  const int l15 = lane & 15;
  const int quad = lane >> 4;
  const int bh = blockIdx.y, b = bh >> 3, h = bh & 7;
  const h16_t* kb = (blockIdx.z ? k1 : k0) + (size_t)bh * 65536;
  const h16_t* vb = (blockIdx.z ? v1 : v0) + (size_t)bh * 65536;
  h16_t* out = blockIdx.z ? out1 : out0;

  __shared__ h16_t kls[2 * 4096];
  __shared__ h16_t vls[2 * 4096];

  const int q0r = blockIdx.x * 128 + wv * 32;
  h16x8 qa[2][2];
#pragma unroll
  for (int t = 0; t < 2; ++t)
#pragma unroll
    for (int s = 0; s < 2; ++s)
      qa[t][s] = *(const h16x8*)(q + ((size_t)bh * 1024 + q0r + t * 16 + l15) * 64 + s * 32 + quad * 8);

  int ksrc[2], vsrc[2], ldst[2];
#pragma unroll
  for (int i = 0; i < 2; ++i) {
    const int L = threadIdx.x + i * 256;
    const int row = L >> 3, cs = L & 7;
    const int c = cs ^ SWKEY(row);
    ksrc[i] = row * 64 + c * 8;
    vsrc[i] = row * 1024 + c * 8;
    ldst[i] = L * 8;
  }

  int kfo[2][4], vfo[2][4];
#pragma unroll
  for (int s = 0; s < 2; ++s)
#pragma unroll
    for (int nt = 0; nt < 4; ++nt) {
      const int r = (nt & 1) * 32 + (l15 >> 2) * 8 + (nt >> 1) * 4 + (l15 & 3);
      kfo[s][nt] = (r * 8 + ((s * 4 + quad) ^ SWKEY(r))) * 8;
      const int d = nt * 16 + l15;
      vfo[s][nt] = (d * 8 + ((s * 4 + quad) ^ SWKEY(d))) * 8;
    }

  f32x4 oaT[2][4];
#pragma unroll
  for (int t = 0; t < 2; ++t)
#pragma unroll
    for (int j = 0; j < 4; ++j) oaT[t][j] = f32x4{0.f, 0.f, 0.f, 0.f};
  float l_part[2] = {0.f, 0.f};

  h16x8 kr[2], vr[2];
#pragma unroll
  for (int i = 0; i < 2; ++i) {
    kr[i] = *(const h16x8*)(kb + ksrc[i]);
    vr[i] = *(const h16x8*)(vb + vsrc[i]);
  }
#pragma unroll
  for (int i = 0; i < 2; ++i) {
    *(h16x8*)(kls + ldst[i]) = kr[i];
    *(h16x8*)(vls + ldst[i]) = vr[i];
  }
  __syncthreads();

  for (int mt = 0; mt < 16; ++mt) {
    const int cur = (mt & 1) * 4096;
    if (mt < 15) {
      const int mm1 = (mt + 1) * 64;
#pragma unroll
      for (int i = 0; i < 2; ++i) {
        kr[i] = *(const h16x8*)(kb + mm1 * 64 + ksrc[i]);
        vr[i] = *(const h16x8*)(vb + mm1 + vsrc[i]);
      }
    }
    f32x4 sfT[2][4];
#pragma unroll
    for (int t = 0; t < 2; ++t)
#pragma unroll
      for (int j = 0; j < 4; ++j) sfT[t][j] = f32x4{0.f, 0.f, 0.f, 0.f};
#pragma unroll
    for (int s = 0; s < 2; ++s)
#pragma unroll
      for (int nt = 0; nt < 4; ++nt) {
        h16x8 kf = *(const h16x8*)(kls + cur + kfo[s][nt]);
        sfT[0][nt] = mfma16(kf, qa[0][s], sfT[0][nt]);
        sfT[1][nt] = mfma16(kf, qa[1][s], sfT[1][nt]);
      }
    int pk[2][4][2];
#pragma unroll
    for (int t = 0; t < 2; ++t)
#pragma unroll
      for (int nt = 0; nt < 4; ++nt) {
        const float e0 = __expf(sfT[t][nt][0] * 0.125f);
        const float e1 = __expf(sfT[t][nt][1] * 0.125f);
        const float e2 = __expf(sfT[t][nt][2] * 0.125f);
        const float e3 = __expf(sfT[t][nt][3] * 0.125f);
        l_part[t] += (e0 + e1) + (e2 + e3);
        pk[t][nt][0] = __builtin_bit_cast(int, __builtin_amdgcn_cvt_pkrtz(e0, e1));
        pk[t][nt][1] = __builtin_bit_cast(int, __builtin_amdgcn_cvt_pkrtz(e2, e3));
      }
#pragma unroll
    for (int s = 0; s < 2; ++s) {
      int4 b0 = {pk[0][s][0], pk[0][s][1], pk[0][s + 2][0], pk[0][s + 2][1]};
      int4 b1 = {pk[1][s][0], pk[1][s][1], pk[1][s + 2][0], pk[1][s + 2][1]};
      h16x8 bf0 = __builtin_bit_cast(h16x8, b0);
      h16x8 bf1 = __builtin_bit_cast(h16x8, b1);
#pragma unroll
      for (int nt = 0; nt < 4; ++nt) {
        h16x8 vf = *(const h16x8*)(vls + cur + vfo[s][nt]);
        oaT[0][nt] = mfma16(vf, bf0, oaT[0][nt]);
        oaT[1][nt] = mfma16(vf, bf1, oaT[1][nt]);
      }
    }
    if (mt < 15) {
      const int nxt = ((mt + 1) & 1) * 4096;
#pragma unroll
      for (int i = 0; i < 2; ++i) {
        *(h16x8*)(kls + nxt + ldst[i]) = kr[i];
        *(h16x8*)(vls + nxt + ldst[i]) = vr[i];
      }
    }
    __syncthreads();
  }

  float sq[16];
#pragma unroll
  for (int i = 0; i < 16; ++i) sq[i] = 0.f;
#pragma unroll
  for (int t = 0; t < 2; ++t) {
    float l = l_part[t] + __shfl_xor(l_part[t], 16, 64);
    l += __shfl_xor(l, 32, 64);
    const float iv = 1.f / l;
    h16_t* obase = out + ((size_t)b * 1024 + q0r + t * 16 + l15) * 512 + h * 64 + quad * 4;
#pragma unroll
    for (int nt = 0; nt < 4; ++nt) {
      h16x4 o;
#pragma unroll
      for (int r = 0; r < 4; ++r) {
        const float v = oaT[t][nt][r] * iv;
        o[r] = (h16_t)v;
        sq[nt * 4 + r] += v * v;
      }
      *(h16x4*)(obase + nt * 16) = o;
    }
  }
  if (blockIdx.z) {
#pragma unroll
    for (int i = 0; i < 16; ++i) {
      sq[i] += __shfl_xor(sq[i], 1, 64);
      sq[i] += __shfl_xor(sq[i], 2, 64);
      sq[i] += __shfl_xor(sq[i], 4, 64);
      sq[i] += __shfl_xor(sq[i], 8, 64);
    }
    if (l15 == 0) {
      float* pp = part2 + (size_t)((b * 8 + blockIdx.x) * 4 + wv) * 512 + h * 64 + quad * 4;
#pragma unroll
      for (int nt = 0; nt < 4; ++nt)
#pragma unroll
        for (int r = 0; r < 4; ++r) pp[nt * 16 + r] = sq[nt * 4 + r];
    }
  }
}

// ---------------------------------------------------------------------------
// Token-axis L2 norms
// ---------------------------------------------------------------------------
__global__ __launch_bounds__(384) void k_cn_p1(const float* __restrict__ ck,
                                               const float* __restrict__ cv,
                                               float* __restrict__ part) {
  const int b = blockIdx.x, ch = blockIdx.y, z = blockIdx.z, f = threadIdx.x;
  const int h = f >> 6, d = f & 63;
  const float* p = (z ? cv : ck) + ((size_t)(b * 6 + h) * 1024 + ch * 16) * 64 + d;
  float s = 0.f;
#pragma unroll
  for (int n = 0; n < 16; ++n) {
    const float v = p[(size_t)n * 64];
    s += v * v;
  }
  part[(size_t)z * 196608 + (size_t)(b * 64 + ch) * 384 + f] = s;
}

__global__ __launch_bounds__(384) void k_cn_p2(const float* __restrict__ part,
                                               float* __restrict__ invck) {
  const int b = blockIdx.x, z = blockIdx.y, f = threadIdx.x;
  float s = 0.f;
#pragma unroll 8
  for (int ch = 0; ch < 64; ++ch)
    s += part[(size_t)z * 196608 + (size_t)(b * 64 + ch) * 384 + f];
  invck[z * 3072 + b * 384 + f] = 1.f / fmaxf(sqrtf(s), 1e-12f);
}

__global__ __launch_bounds__(512) void k_rm_p2(const float* __restrict__ part2,
                                               float* __restrict__ invrm) {
  const int b = blockIdx.x, f = threadIdx.x;
  float s = 0.f;
#pragma unroll 8
  for (int j = 0; j < 32; ++j) s += part2[(size_t)(b * 32 + j) * 512 + f];
  invrm[b * 512 + f] = 1.f / fmaxf(sqrtf(s), 1e-12f);
}

// ---------------------------------------------------------------------------
// 10 dispatches. Buffers: S0=Q S1=Kself S2=vTself S3=ck1mid->ctxout
// S4=cv1mid->nlout S5=ckh T0(d_out lo)=ck0mid->cvT T1(d_out hi)=cv0mid->ATTN.
// ws: inv_ck@0(24K) inv_rm@32K(16K) partck@64K(1.5M) part2@1.75M(512K)
// slots @3MB (6x8MB) -> ~51MB total.
// ---------------------------------------------------------------------------
extern "C" void kernel_launch(void* const* d_in, const int* in_sizes, int n_in,
                              void* d_out, int out_size, void* d_ws, size_t ws_size,
                              hipStream_t stream) {
  (void)in_sizes; (void)n_in; (void)out_size; (void)ws_size;
  const float* x     = (const float*)d_in[0];
  const float* ck    = (const float*)d_in[1];
  const float* cv    = (const float*)d_in[2];
  const float* w_qkv = (const float*)d_in[3];
  const float* w_out = (const float*)d_in[4];
  const float* b_out = (const float*)d_in[5];
  const float* ckw0  = (const float*)d_in[6];
  const float* ckb0  = (const float*)d_in[7];
  const float* ckw1  = (const float*)d_in[8];
  const float* ckb1  = (const float*)d_in[9];
  const float* ckw2  = (const float*)d_in[10];
  const float* ckb2  = (const float*)d_in[11];
  const float* cvw0  = (const float*)d_in[12];
  const float* cvb0  = (const float*)d_in[13];
  const float* cvw1  = (const float*)d_in[14];
  const float* cvb1  = (const float*)d_in[15];
  const float* cvw2  = (const float*)d_in[16];
  const float* cvb2  = (const float*)d_in[17];
  const float* nl_w  = (const float*)d_in[18];
  const float* nl_b  = (const float*)d_in[19];
  const float* subr  = (const float*)d_in[20];

  const size_t MB = 1024 * 1024;
  char* p = (char*)d_ws;
  float* invck = (float*)p;                        // 24 KB
  float* invrm = (float*)(p + 32 * 1024);          // 16 KB
  float* partck = (float*)(p + 64 * 1024);         // 1.5 MB
  float* part2 = (float*)(p + 1792 * 1024);        // 512 KB
  h16_t* S0 = (h16_t*)(p + 3 * MB + 0 * 8 * MB);
  h16_t* S1 = (h16_t*)(p + 3 * MB + 1 * 8 * MB);
  h16_t* S2 = (h16_t*)(p + 3 * MB + 2 * 8 * MB);
  h16_t* S3 = (h16_t*)(p + 3 * MB + 3 * 8 * MB);
  h16_t* S4 = (h16_t*)(p + 3 * MB + 4 * 8 * MB);
  h16_t* S5 = (h16_t*)(p + 3 * MB + 5 * 8 * MB);
  h16_t* T0 = (h16_t*)d_out;
  h16_t* T1 = (h16_t*)d_out + 4194304;

  const dim3 blk(256);
  // 1. token-norm partials + finalize (ck & cv together)
  k_cn_p1<<<dim3(8, 64, 2), 384, 0, stream>>>(ck, cv, partck);
  k_cn_p2<<<dim3(8, 2), 384, 0, stream>>>(partck, invck);
  // 2. qkv projection (f32 in)
  k_gemm_qkv<<<dim3(128, 24), blk, 0, stream>>>(x, w_qkv, S0, S1, S2);
  // 3. style-vectorizer chains, z-merged
  k_gemm_l0<<<dim3(128, 8, 2), blk, 0, stream>>>(ck, cv, invck, ckw0, cvw0, ckb0, cvb0, T0, T1);
  k_gemm_l1<<<dim3(128, 8, 2), blk, 0, stream>>>(T0, T1, ckw1, cvw1, ckb1, cvb1, S3, S4);
  k_gemm_l2<<<dim3(128, 8, 2), blk, 0, stream>>>(S3, S4, ckw2, cvw2, ckb2, cvb2, S5, T0);
  // 4. merged attention: self -> T1 (ATTN), context -> S3 (+ rm partials)
  k_attn4<<<dim3(8, 64, 2), blk, 0, stream>>>(S0, S1, S2, T1, S5, T0, S3, part2);
  // 5. rm-norm finalize
  k_rm_p2<<<8, 512, 0, stream>>>(part2, invrm);
  // 6. nl GEMM (fused normalize) + combine with ATTN -> S4
  k_gemm_nl<<<dim3(128, 8), blk, 0, stream>>>(S3, invrm, nl_w, nl_b, T1, subr, S4);
  // 7. final projection -> d_out (f32)
  k_gemm_out<<<dim3(128, 8), blk, 0, stream>>>(S4, w_out, b_out, (float*)d_out);
}